// Round 3
// baseline (326.932 us; speedup 1.0000x reference)
//
#include <hip/hip_runtime.h>

#define DFEAT 64
#define EPSBN 1e-5f
#define SCB 2048      // elements per scan block (256 threads x 8)
#define CHUNK_LG 15
#define CHUNK (1 << CHUNK_LG)   // 32768 edges per chunk
#define RNG 8192      // nodes per partition (one packed 32KB LDS histogram)

// ---------------- LDS-privatized PACKED dual histogram + chunk-local rank ----------------
// one 32KB LDS array: low16 = dst count, high16 = src count. int4 edge loads +
// manual prefetch. Grid is (P, C): the P partition-blocks of one chunk dispatch
// together -> the 256KB chunk is read once into L2 per XCD and shared, instead
// of 13 temporally-spread full re-reads served by L3.
__global__ __launch_bounds__(256) void hist2d_kernel(
        const int* __restrict__ src, const int* __restrict__ dst,
        unsigned short* __restrict__ lrank, unsigned short* __restrict__ cnt,
        int* __restrict__ deg_out, int E, int N, int N_pad) {
    __shared__ int h[RNG];
    int tid = threadIdx.x;
    int c = blockIdx.y, p = blockIdx.x;
    int nbeg = p * RNG;
    for (int i = tid; i < RNG; i += 256) h[i] = 0;
    __syncthreads();

    int ebeg = c << CHUNK_LG;
    int eend = min(ebeg + CHUNK, E);
    int nvec = (eend - ebeg) >> 2;              // full int4 groups
    const int4* src4 = (const int4*)(src + ebeg);
    const int4* dst4 = (const int4*)(dst + ebeg);

    int i = tid;
    int4 s4 = make_int4(0, 0, 0, 0), d4 = s4;
    if (i < nvec) { s4 = src4[i]; d4 = dst4[i]; }
    while (i < nvec) {
        int inext = i + 256;
        int4 sn = make_int4(0, 0, 0, 0), dn = sn;
        if (inext < nvec) { sn = src4[inext]; dn = dst4[inext]; }   // prefetch
        int e = ebeg + (i << 2);
        {
            unsigned int so, dof;
            so = (unsigned int)(s4.x - nbeg); if (so < RNG) atomicAdd(&h[so], 0x10000);
            so = (unsigned int)(s4.y - nbeg); if (so < RNG) atomicAdd(&h[so], 0x10000);
            so = (unsigned int)(s4.z - nbeg); if (so < RNG) atomicAdd(&h[so], 0x10000);
            so = (unsigned int)(s4.w - nbeg); if (so < RNG) atomicAdd(&h[so], 0x10000);
            dof = (unsigned int)(d4.x - nbeg);
            if (dof < RNG) lrank[e + 0] = (unsigned short)(atomicAdd(&h[dof], 1) & 0xffff);
            dof = (unsigned int)(d4.y - nbeg);
            if (dof < RNG) lrank[e + 1] = (unsigned short)(atomicAdd(&h[dof], 1) & 0xffff);
            dof = (unsigned int)(d4.z - nbeg);
            if (dof < RNG) lrank[e + 2] = (unsigned short)(atomicAdd(&h[dof], 1) & 0xffff);
            dof = (unsigned int)(d4.w - nbeg);
            if (dof < RNG) lrank[e + 3] = (unsigned short)(atomicAdd(&h[dof], 1) & 0xffff);
        }
        s4 = sn; d4 = dn; i = inext;
    }
    for (int e = ebeg + (nvec << 2) + tid; e < eend; e += 256) {
        unsigned int so = (unsigned int)(src[e] - nbeg);
        unsigned int dof = (unsigned int)(dst[e] - nbeg);
        if (so < RNG) atomicAdd(&h[so], 0x10000);
        if (dof < RNG) lrank[e] = (unsigned short)(atomicAdd(&h[dof], 1) & 0xffff);
    }
    __syncthreads();

    for (int i2 = tid; i2 < RNG; i2 += 256) {
        int n = nbeg + i2;
        if (n < N) {
            unsigned int v = (unsigned int)h[i2];
            unsigned int vo = v >> 16;
            if (vo) atomicAdd(&deg_out[n], (int)vo);   // contiguous lanes -> batched
            cnt[(size_t)c * N_pad + n] = (unsigned short)(v & 0xffffu);
        }
    }
}

// ---------------- column scan: per-node exclusive prefix over chunks ----------------
__global__ void colscan_kernel(unsigned short* __restrict__ cnt,
                               int* __restrict__ deg_in, int N, int N_pad, int C) {
    int n = blockIdx.x * blockDim.x + threadIdx.x;
    if (n >= N) return;
    int run = 0;
    for (int c = 0; c < C; ++c) {
        size_t idx = (size_t)c * N_pad + n;
        int v = cnt[idx];
        cnt[idx] = (unsigned short)run;
        run += v;
    }
    deg_in[n] = run;
}

// ---------------- scan pass 1: per-block sums of deg_in ----------------
__global__ void scan1_kernel(const int* __restrict__ deg, int* __restrict__ bsum, int N) {
    __shared__ int red[256];
    int t = threadIdx.x;
    int base = blockIdx.x * SCB + t * 8;
    int s = 0;
    #pragma unroll
    for (int j = 0; j < 8; ++j) { int idx = base + j; if (idx < N) s += deg[idx]; }
    red[t] = s;
    __syncthreads();
    for (int d = 128; d > 0; d >>= 1) { if (t < d) red[t] += red[t + d]; __syncthreads(); }
    if (t == 0) bsum[blockIdx.x] = red[0];
}

// ---------------- scan pass 2: one-wave shuffle exclusive scan (NB <= 64) ----------------
__global__ void scan2_kernel(int* __restrict__ bsum, int* __restrict__ row_start, int NB, int N) {
    int lane = threadIdx.x & 63;
    int v = (lane < NB) ? bsum[lane] : 0;
    int incl = v;
    #pragma unroll
    for (int off = 1; off < 64; off <<= 1) {
        int t = __shfl_up(incl, off);
        if (lane >= off) incl += t;
    }
    if (lane < NB) bsum[lane] = incl - v;
    if (lane == 63) row_start[N] = incl;   // total == E
}

// ---------------- scan pass 3: full exclusive scan -> row_start ----------------
__global__ void scan3_kernel(const int* __restrict__ deg, const int* __restrict__ bsum,
                             int* __restrict__ row_start, int N) {
    __shared__ int sc[256];
    int t = threadIdx.x;
    int base = blockIdx.x * SCB + t * 8;
    int v[8], ex[8];
    int s = 0;
    #pragma unroll
    for (int j = 0; j < 8; ++j) {
        int idx = base + j;
        v[j] = (idx < N) ? deg[idx] : 0;
        ex[j] = s;
        s += v[j];
    }
    sc[t] = s;
    __syncthreads();
    for (int d = 1; d < 256; d <<= 1) {
        int vv = (t >= d) ? sc[t - d] : 0;
        __syncthreads();
        sc[t] += vv;
        __syncthreads();
    }
    int toff = sc[t] - s + bsum[blockIdx.x];
    #pragma unroll
    for (int j = 0; j < 8; ++j) {
        int idx = base + j;
        if (idx < N) row_start[idx] = toff + ex[j];
    }
}

// ---------------- place edges: slot = row_start[d] + pref[c][d] + lrank[e] ----------------
__global__ void fill_kernel(const int* __restrict__ src, const int* __restrict__ dst,
                            const unsigned short* __restrict__ lrank,
                            const unsigned short* __restrict__ cnt,
                            const int* __restrict__ deg_out, const int* __restrict__ row_start,
                            int2* __restrict__ epack, int E, int N_pad) {
    int e = blockIdx.x * blockDim.x + threadIdx.x;
    if (e < E) {
        int d = dst[e], s = src[e];
        int c = e >> CHUNK_LG;
        float coef = rsqrtf((float)max(deg_out[s], 1));
        int slot = row_start[d] + (int)cnt[(size_t)c * N_pad + d] + (int)lrank[e];
        epack[slot] = make_int2(s, __float_as_int(coef));
    }
}

// ---------------- fused SpMM + GEMM + BN partials: 4 rows per wave ----------------
// Round-2 post-mortem: the GEMM tail re-streamed all 16KB of W from LDS per
// row (1.6GB LDS traffic, ~21us floor at 128B/cyc/CU), and the edge loop's
// __shfl broadcasts burned the LDS pipe with ds_bpermute. Fixes:
//  * 4 rows per wave -> each Wl[k][lane] ds_read feeds 4 FMAs (LDS bytes /4)
//  * v_readlane (uniform lane idx) replaces ds_bpermute: VALU-cheap, yields
//    SGPR src/coef -> gather becomes saddr-form, coef a scalar FMA operand
//  * BN column partials accumulated in registers (lane == column), one LDS
//    tree + 128-float partial store per block (kills bnstat1's 25.6MB re-read)
__global__ __launch_bounds__(256, 8) void spmm_gemm_kernel(
        const float* __restrict__ x, const int* __restrict__ row_start,
        const int2* __restrict__ epack, const float* __restrict__ W,
        const float* __restrict__ bvec, float* __restrict__ y,
        float* __restrict__ partial, int N) {
    __shared__ float Wl[DFEAT * DFEAT];
    __shared__ float red_s[4][DFEAT];
    __shared__ float red_q[4][DFEAT];
    int tid = threadIdx.x;
    {
        const float4* W4 = (const float4*)W;
        float4* Wl4 = (float4*)Wl;
        #pragma unroll
        for (int j = 0; j < 4; ++j) Wl4[tid + 256 * j] = W4[tid + 256 * j];
    }
    __syncthreads();

    int lane = tid & 63;
    int w = tid >> 6;
    int r0 = blockIdx.x * 16 + w * 4;
    float bv = bvec[lane];

    float acc[4];
    #pragma unroll
    for (int q = 0; q < 4; ++q) {
        float a = 0.f;
        int r = r0 + q;
        if (r < N) {
            int beg = row_start[r];
            int end = row_start[r + 1];
            for (int cb = beg; cb < end; cb += 64) {
                int take = min(64, end - cb);
                int2 p = (lane < take) ? epack[cb + lane] : make_int2(0, 0);
                int j = 0;
                for (; j + 8 <= take; j += 8) {
                    int sj[8]; float cj[8], v[8];
                    #pragma unroll
                    for (int u = 0; u < 8; ++u) {
                        sj[u] = __builtin_amdgcn_readlane(p.x, j + u);
                        cj[u] = __int_as_float(__builtin_amdgcn_readlane(p.y, j + u));
                    }
                    #pragma unroll
                    for (int u = 0; u < 8; ++u) v[u] = x[(size_t)sj[u] * DFEAT + lane];
                    #pragma unroll
                    for (int u = 0; u < 8; ++u) a = fmaf(v[u], cj[u], a);
                }
                for (; j < take; ++j) {
                    int s = __builtin_amdgcn_readlane(p.x, j);
                    float c = __int_as_float(__builtin_amdgcn_readlane(p.y, j));
                    a = fmaf(x[(size_t)s * DFEAT + lane], c, a);
                }
            }
            a *= rsqrtf((float)max(end - beg, 1));   // norm_dst: a = agg[r][lane]
        }
        acc[q] = a;
    }

    // ---- in-wave GEMM tail, W read shared by 4 rows:
    //      y[r][lane] = b[lane] + sum_k agg[r][k] * W[k][lane]
    float yo0 = 0.f, yo1 = 0.f, yo2 = 0.f, yo3 = 0.f;
    int ai0 = __float_as_int(acc[0]);
    int ai1 = __float_as_int(acc[1]);
    int ai2 = __float_as_int(acc[2]);
    int ai3 = __float_as_int(acc[3]);
    #pragma unroll 8
    for (int k = 0; k < DFEAT; ++k) {
        float wk = Wl[k * DFEAT + lane];     // conflict-free, 1 read / 4 rows
        yo0 = fmaf(__int_as_float(__builtin_amdgcn_readlane(ai0, k)), wk, yo0);
        yo1 = fmaf(__int_as_float(__builtin_amdgcn_readlane(ai1, k)), wk, yo1);
        yo2 = fmaf(__int_as_float(__builtin_amdgcn_readlane(ai2, k)), wk, yo2);
        yo3 = fmaf(__int_as_float(__builtin_amdgcn_readlane(ai3, k)), wk, yo3);
    }

    float yq[4] = {yo0, yo1, yo2, yo3};
    float ps = 0.f, pq = 0.f;                // column (=lane) partial stats
    #pragma unroll
    for (int q = 0; q < 4; ++q) {
        int r = r0 + q;
        if (r < N) {
            float yv = bv + yq[q];
            y[(size_t)r * DFEAT + lane] = yv;
            ps += yv;
            pq = fmaf(yv, yv, pq);
        }
    }

    red_s[w][lane] = ps;
    red_q[w][lane] = pq;
    __syncthreads();
    if (w == 0) {
        float s = red_s[0][lane] + red_s[1][lane] + red_s[2][lane] + red_s[3][lane];
        float q2 = red_q[0][lane] + red_q[1][lane] + red_q[2][lane] + red_q[3][lane];
        float* p = partial + (size_t)blockIdx.x * 128;
        p[lane] = s;
        p[64 + lane] = q2;
    }
}

// ---------------- BN stats finalize: G partials -> sums/sumsq (adjacent) ----------------
// 16 blocks x 32 stripes; 16 atomics per address (trivial serialization).
__global__ void bnstat2_kernel(const float* __restrict__ partial,
                               float* __restrict__ sums, int G) {
    int t = threadIdx.x;
    int j = t & 127, h = t >> 7;
    int stripe = blockIdx.x * 2 + h;         // 0..31
    float s = 0.f;
    for (int g = stripe; g < G; g += 32)
        s += partial[(size_t)g * 128 + j];
    __shared__ float red[2][128];
    red[h][j] = s;
    __syncthreads();
    if (h == 0) atomicAdd(&sums[j], red[0][j] + red[1][j]);   // sums||sumsq contiguous
}

// ---------------- BN (batch stats) + ReLU + residual, float4, in place on y ----------------
__global__ void bn_relu_res_kernel(const float* __restrict__ x,
                                   const float* __restrict__ sums,
                                   const float* __restrict__ sumsq,
                                   const float* __restrict__ gamma,
                                   const float* __restrict__ beta,
                                   float* __restrict__ y, int n4, float inv_n) {
    int i = blockIdx.x * blockDim.x + threadIdx.x;   // float4 index
    if (i < n4) {
        int c0 = (i << 2) & (DFEAT - 1);
        float4 yv = ((const float4*)y)[i];
        float4 xv = ((const float4*)x)[i];
        float o[4] = {yv.x, yv.y, yv.z, yv.w};
        float xi[4] = {xv.x, xv.y, xv.z, xv.w};
        #pragma unroll
        for (int k = 0; k < 4; ++k) {
            int c = c0 + k;
            float mean = sums[c] * inv_n;
            float var = sumsq[c] * inv_n - mean * mean;
            float inv = rsqrtf(var + EPSBN);
            float v = (o[k] - mean) * inv * gamma[c] + beta[c];
            o[k] = xi[k] + fmaxf(v, 0.f);
        }
        ((float4*)y)[i] = make_float4(o[0], o[1], o[2], o[3]);
    }
}

extern "C" void kernel_launch(void* const* d_in, const int* in_sizes, int n_in,
                              void* d_out, int out_size, void* d_ws, size_t ws_size,
                              hipStream_t stream) {
    const float* x     = (const float*)d_in[0];
    const int*   src   = (const int*)d_in[1];
    const int*   dst   = (const int*)d_in[2];
    const float* W     = (const float*)d_in[3];
    const float* bvec  = (const float*)d_in[4];
    const float* gamma = (const float*)d_in[5];
    const float* beta  = (const float*)d_in[6];
    float* out = (float*)d_out;   // y, written once by fused spmm+gemm

    const int n_nodes = in_sizes[0] / DFEAT;
    const int E = in_sizes[1];
    const int NB = (n_nodes + SCB - 1) / SCB;
    const int C = (E + CHUNK - 1) >> CHUNK_LG;          // edge chunks
    const int P = (n_nodes + RNG - 1) / RNG;            // node partitions
    const int N_pad = P * RNG;

    // ws: epack (E int2) | lrank (E u16) | cnt (C*N_pad u16) | deg_out N |
    //     sums 64 | sumsq 64 | deg_in N | row_start N+1 | bsum 64
    char* wsb = (char*)d_ws;
    int2* epack          = (int2*)wsb;
    unsigned short* lrank = (unsigned short*)(wsb + (size_t)E * 8);
    unsigned short* cnt   = lrank + E;
    int*  deg_out_i  = (int*)(cnt + (size_t)C * N_pad);
    float* sums      = (float*)(deg_out_i + n_nodes);
    float* sumsq     = sums + DFEAT;
    int*  deg_in_i   = (int*)(sumsq + DFEAT);
    int*  row_start  = deg_in_i + n_nodes;
    int*  bsum       = row_start + n_nodes + 1;
    // partial aliases the cnt region (dead after fill_kernel): needs
    // grid16*512B = N/16*512 = 32N bytes <= 2*C*N_pad bytes. 3.2MB here.
    float* partial   = (float*)cnt;

    // zero: deg_out + sums + sumsq (contiguous; bnstat2 atomic-accumulates).
    hipMemsetAsync(deg_out_i, 0, ((size_t)n_nodes + 2 * DFEAT) * sizeof(int), stream);

    hist2d_kernel<<<dim3(P, C), 256, 0, stream>>>(src, dst, lrank, cnt, deg_out_i,
                                                  E, n_nodes, N_pad);

    colscan_kernel<<<(n_nodes + 255) / 256, 256, 0, stream>>>(cnt, deg_in_i,
                                                              n_nodes, N_pad, C);

    scan1_kernel<<<NB, 256, 0, stream>>>(deg_in_i, bsum, n_nodes);
    scan2_kernel<<<1, 64, 0, stream>>>(bsum, row_start, NB, n_nodes);
    scan3_kernel<<<NB, 256, 0, stream>>>(deg_in_i, bsum, row_start, n_nodes);

    fill_kernel<<<(E + 255) / 256, 256, 0, stream>>>(src, dst, lrank, cnt, deg_out_i,
                                                     row_start, epack, E, N_pad);

    int grid_sg = (n_nodes + 15) / 16;
    spmm_gemm_kernel<<<grid_sg, 256, 0, stream>>>(x, row_start, epack,
                                                  W, bvec, out, partial, n_nodes);

    bnstat2_kernel<<<16, 256, 0, stream>>>(partial, sums, grid_sg);

    int n4 = n_nodes * DFEAT / 4;
    bn_relu_res_kernel<<<(n4 + 255) / 256, 256, 0, stream>>>(
        x, sums, sumsq, gamma, beta, out, n4, 1.0f / (float)n_nodes);
}